// Round 4
// baseline (1435.802 us; speedup 1.0000x reference)
//
#include <hip/hip_runtime.h>
#include <math.h>

#define NB 16
#define CC 576
#define HH 12
#define WW 20
#define PP 240
#define MM 3840
#define NHEAD 8
#define HALO 22

typedef __attribute__((ext_vector_type(8))) short short8;
typedef __attribute__((ext_vector_type(4))) float floatx4;
typedef unsigned short ushort_t;

__device__ __forceinline__ float sigmoidf_(float x) {
    return 1.0f / (1.0f + expf(-x));
}
__device__ __forceinline__ unsigned short f2bf(float x) {
    union { float f; unsigned u; } v; v.f = x;
    unsigned r = v.u + 0x7fff + ((v.u >> 16) & 1);
    return (unsigned short)(r >> 16);
}
__device__ __forceinline__ float bf2f(unsigned short b) {
    union { float f; unsigned u; } v; v.u = ((unsigned)b) << 16;
    return v.f;
}

// ---------------- Kernel A: channel means + linear head + single_out ------
__global__ __launch_bounds__(256) void k_single(const float* __restrict__ f,
                                                const float* __restrict__ linW,
                                                const float* __restrict__ linb,
                                                float* __restrict__ out) {
    int n = blockIdx.x;
    __shared__ float f1[CC];
    __shared__ float lin[10];
    int t = threadIdx.x;
    int lane = t & 63, wave = t >> 6;
    const float* fn = f + (size_t)n * CC * PP;
    for (int c = wave; c < CC; c += 4) {
        const float* row = fn + c * PP;
        float s = 0.f;
        for (int p = lane; p < PP; p += 64) s += row[p];
        #pragma unroll
        for (int off = 32; off; off >>= 1) s += __shfl_xor(s, off, 64);
        if (lane == 0) f1[c] = s * (1.0f / PP);
    }
    __syncthreads();
    if (t < 10) {
        const float* wrow = linW + t * CC;
        float s = linb[t];
        for (int c = 0; c < CC; ++c) s = fmaf(f1[c], wrow[c], s);
        lin[t] = s;
    }
    __syncthreads();
    if (t == 0) {
        const float eps = 1e-5f;
        float conf = sigmoidf_(lin[0]);
        conf = fminf(fmaxf(conf, eps), 1.f - eps);
        int best = 0; float bv = lin[1];
        #pragma unroll
        for (int j = 1; j < 5; ++j) { if (lin[1 + j] > bv) { bv = lin[1 + j]; best = j; } }
        float dist = 3.f * sigmoidf_(lin[6]);
        float offs = tanhf(lin[7]);
        float sev  = fminf(fmaxf(sigmoidf_(lin[8]), eps), 1.f - eps);
        float surf = fminf(fmaxf(sigmoidf_(lin[9]), eps), 1.f - eps);
        float* o = out + n * 6;
        o[0] = conf; o[1] = (float)best; o[2] = dist;
        o[3] = offs; o[4] = sev; o[5] = surf;
    }
}

// ---------------- prep: f[n][c][p] -> ft_hi/ft_lo [m][c] bf16 -------------
__global__ __launch_bounds__(256) void k_prep_f(const float* __restrict__ f,
                                                ushort_t* __restrict__ fhi,
                                                ushort_t* __restrict__ flo) {
    __shared__ float tile[32][33];
    int c0 = blockIdx.x * 32, p0 = blockIdx.y * 32, n = blockIdx.z;
    int tp = threadIdx.x & 31, tc8 = threadIdx.x >> 5;
    for (int cc = tc8; cc < 32; cc += 8) {
        int p = p0 + tp;
        tile[cc][tp] = (p < PP) ? f[((size_t)n * CC + c0 + cc) * PP + p] : 0.f;
    }
    __syncthreads();
    int tcw = threadIdx.x & 31, tpw = threadIdx.x >> 5;
    for (int pp = tpw; pp < 32; pp += 8) {
        int p = p0 + pp;
        if (p < PP) {
            float v = tile[tcw][pp];
            unsigned short hi = f2bf(v);
            size_t o = ((size_t)n * PP + p) * CC + c0 + tcw;
            fhi[o] = hi;
            flo[o] = f2bf(v - bf2f(hi));
        }
    }
}

// ------ prep: w1[h][co][ci][tap] -> chunked [h][tap][cib][co][ci8x4] ------
// Coalesced read of the full (h,co) 5184-float row via LDS, then write
// hi/lo bf16 in the conv kernel's B-fragment-contiguous layout:
//   whi[ ((h*9+tap)*18 + cib)*CC*32 + co*32 + (ci&31) ]
__global__ __launch_bounds__(256) void k_prep_w(const float* __restrict__ w1,
                                                ushort_t* __restrict__ whi,
                                                ushort_t* __restrict__ wlo) {
    __shared__ float buf[5184];
    int co = blockIdx.x % CC;
    int h  = blockIdx.x / CC;
    const float* src = w1 + (size_t)(h * CC + co) * 5184;
    int t = threadIdx.x;
    for (int i = t; i < 1296; i += 256)
        *(float4*)(buf + 4 * i) = *(const float4*)(src + 4 * i);
    __syncthreads();
    for (int idx = t; idx < 5184; idx += 256) {
        int tap = idx / CC;
        int ci  = idx - tap * CC;
        float v = buf[ci * 9 + tap];
        unsigned short hi = f2bf(v);
        int cib = ci >> 5, cr = ci & 31;
        size_t o = (((size_t)(h * 9 + tap) * 18 + cib) * CC + co) * 32 + cr;
        whi[o] = hi;
        wlo[o] = f2bf(v - bf2f(hi));
    }
}

// ---------------- init maps with bias -------------------------------------
__global__ __launch_bounds__(256) void k_maps_init(float* __restrict__ maps,
                                                   const float* __restrict__ b2) {
    int i = blockIdx.x * 256 + threadIdx.x;
    if (i < NB * 14 * PP) {
        int o = (i / PP) % 14;
        maps[i] = b2[o];
    }
}

// ---------------- fused MFMA conv (bf16x3) + BN + SiLU + projection -------
// grid (15, 9, 8): m-tile 256, co-tile 64, head. 4 waves, wave-tile 64x64.
// A (halo-staged, shared across 9 taps) in LDS only; B fragments loaded
// DIRECTLY from global (fragment-contiguous layout, L1-served across waves).
// 2 barriers per ci-chunk. 3 MFMA passes (hi*hi, hi*lo, lo*hi).
__global__ __launch_bounds__(256, 4) void k_conv_mfma(
        const ushort_t* __restrict__ fhi, const ushort_t* __restrict__ flo,
        const ushort_t* __restrict__ whi, const ushort_t* __restrict__ wlo,
        const float* __restrict__ w2,
        const float* __restrict__ bng, const float* __restrict__ bnb,
        const float* __restrict__ bnm, const float* __restrict__ bnv,
        float* __restrict__ maps) {
    // fragment-order LDS: chunk(row,g) = (row>>4)*64 + g*16 + (row&15)
    __shared__ __align__(16) ushort_t Ah[1216 * 8];   // 304 rows x 32 k
    __shared__ __align__(16) ushort_t Al[1216 * 8];

    int t = threadIdx.x;
    int m0 = blockIdx.x * 256;
    int c0 = blockIdx.y * 64;
    int h  = blockIdx.z;
    int w = t >> 6, lane = t & 63;
    int quad = lane >> 4, l15 = lane & 15;
    int srow_lo = t & 15, sg = (t >> 4) & 3, srb = t >> 6;

    // zero rows 300..303 (row-block 18, r&15 = 12..15) — never overwritten
    if (t < 32) {
        int arr = t >> 4, g = (t >> 2) & 3, rr = 12 + (t & 3);
        int idx = 18 * 64 + g * 16 + rr;
        short8 z = {0, 0, 0, 0, 0, 0, 0, 0};
        *(short8*)((arr ? Al : Ah) + idx * 8) = z;
    }

    // per-lane A-fragment geometry (i = 0..3)
    int ybase[4], xbase[4], mlb[4];
    #pragma unroll
    for (int i = 0; i < 4; ++i) {
        int ml = w * 64 + i * 16 + l15;
        int m = m0 + ml;
        int p = m % PP;
        ybase[i] = p / WW;
        xbase[i] = p - ybase[i] * WW;
        mlb[i] = ml + HALO;
    }

    floatx4 acc[4][4];
    #pragma unroll
    for (int i = 0; i < 4; ++i)
        #pragma unroll
        for (int j = 0; j < 4; ++j) acc[i][j] = (floatx4){0.f, 0.f, 0.f, 0.f};

    for (int cib = 0; cib < 18; ++cib) {
        __syncthreads();
        int koff = cib * 32 + sg * 8;
        #pragma unroll
        for (int it = 0; it < 5; ++it) {
            int row = (srb + 4 * it) * 16 + srow_lo;
            if (row < 300) {
                int mg = m0 - HALO + row;
                int cidx = 256 * it + t;
                short8 vh = {0, 0, 0, 0, 0, 0, 0, 0};
                short8 vl = {0, 0, 0, 0, 0, 0, 0, 0};
                if ((unsigned)mg < (unsigned)MM) {
                    vh = *(const short8*)(fhi + (size_t)mg * CC + koff);
                    vl = *(const short8*)(flo + (size_t)mg * CC + koff);
                }
                *(short8*)(Ah + cidx * 8) = vh;
                *(short8*)(Al + cidx * 8) = vl;
            }
        }
        __syncthreads();

        for (int tap = 0; tap < 9; ++tap) {
            int dy = tap / 3 - 1, dx = tap % 3 - 1;
            size_t wbase = (((size_t)(h * 9 + tap) * 18 + cib) * CC) * 32;
            const ushort_t* wbh = whi + wbase;
            const ushort_t* wbl = wlo + wbase;

            short8 ah[4], al[4];
            #pragma unroll
            for (int i = 0; i < 4; ++i) {
                int yy = ybase[i] + dy, xx = xbase[i] + dx;
                int r = ((unsigned)yy < (unsigned)HH && (unsigned)xx < (unsigned)WW)
                          ? (mlb[i] + dy * WW + dx) : (300 + (l15 & 3));
                int a16 = ((r >> 4) * 64 + quad * 16 + (r & 15)) * 8;
                ah[i] = *(const short8*)(Ah + a16);
                al[i] = *(const short8*)(Al + a16);
            }
            #pragma unroll
            for (int j = 0; j < 4; ++j) {
                int off = (c0 + j * 16 + l15) * 32 + quad * 8;
                short8 bh = *(const short8*)(wbh + off);
                short8 bl = *(const short8*)(wbl + off);
                #pragma unroll
                for (int i = 0; i < 4; ++i) {
                    acc[i][j] = __builtin_amdgcn_mfma_f32_16x16x32_bf16(
                        ah[i], bh, acc[i][j], 0, 0, 0);
                    acc[i][j] = __builtin_amdgcn_mfma_f32_16x16x32_bf16(
                        ah[i], bl, acc[i][j], 0, 0, 0);
                    acc[i][j] = __builtin_amdgcn_mfma_f32_16x16x32_bf16(
                        al[i], bh, acc[i][j], 0, 0, 0);
                }
            }
        }
    }

    // ---- epilogue: BN + SiLU, then fused projection ----
    float scale[4], shift[4];
    #pragma unroll
    for (int j = 0; j < 4; ++j) {
        int c = h * CC + c0 + j * 16 + l15;
        float g_ = bng[c], bb = bnb[c], bm = bnm[c], bv = bnv[c];
        scale[j] = g_ / sqrtf(bv + 1e-5f);
        shift[j] = bb - bm * scale[j];
    }
    #pragma unroll
    for (int i = 0; i < 4; ++i)
        #pragma unroll
        for (int j = 0; j < 4; ++j)
            #pragma unroll
            for (int r = 0; r < 4; ++r) {
                float hx = fmaf(acc[i][j][r], scale[j], shift[j]);
                acc[i][j][r] = hx * sigmoidf_(hx);
            }

    static const int OFFo[NHEAD + 1] = {0, 5, 6, 8, 10, 11, 12, 13, 14};
    int o0 = OFFo[h], o1 = OFFo[h + 1];
    for (int o = o0; o < o1; ++o) {
        float w2v[4];
        #pragma unroll
        for (int j = 0; j < 4; ++j) w2v[j] = w2[o * CC + c0 + j * 16 + l15];
        float pv[4][4];
        #pragma unroll
        for (int i = 0; i < 4; ++i)
            #pragma unroll
            for (int r = 0; r < 4; ++r) {
                float s = 0.f;
                #pragma unroll
                for (int j = 0; j < 4; ++j) s = fmaf(acc[i][j][r], w2v[j], s);
                pv[i][r] = s;
            }
        #pragma unroll
        for (int off = 1; off < 16; off <<= 1)
            #pragma unroll
            for (int i = 0; i < 4; ++i)
                #pragma unroll
                for (int r = 0; r < 4; ++r)
                    pv[i][r] += __shfl_xor(pv[i][r], off, 64);
        if (l15 == 0) {
            #pragma unroll
            for (int i = 0; i < 4; ++i)
                #pragma unroll
                for (int r = 0; r < 4; ++r) {
                    int m = m0 + w * 64 + i * 16 + quad * 4 + r;
                    int n = m / PP, p = m - n * PP;
                    atomicAdd(&maps[(n * 14 + o) * PP + p], pv[i][r]);
                }
        }
    }
}

// ---------------- Kernel D: decode + top-k + distance sort ----------------
__global__ __launch_bounds__(256) void k_decode(
        const float* __restrict__ maps,
        const int* __restrict__ fw_p, const int* __restrict__ fh_p,
        float* __restrict__ out) {
    int n = blockIdx.x;
    int t = threadIdx.x;
    __shared__ float ms[14][PP];
    __shared__ float sconf[PP];
    __shared__ float cscore[100];
    __shared__ int   cidx[100];
    __shared__ float dets[100][10];
    __shared__ float dvals[100];

    const float* mp = maps + (size_t)n * 14 * PP;
    for (int idx = t; idx < 14 * PP; idx += 256) ms[idx / PP][idx % PP] = mp[idx];
    __syncthreads();
    if (t < PP) sconf[t] = sigmoidf_(ms[5][t]);
    __syncthreads();

    int wv = t >> 6, lane = t & 63;
    for (int cls = wv; cls < 5; cls += 4) {
        float v[4]; int pi[4];
        #pragma unroll
        for (int j = 0; j < 4; ++j) {
            int p = lane + 64 * j;
            pi[j] = p;
            v[j] = (p < PP) ? sconf[p] * sigmoidf_(ms[cls][p]) : -1e30f;
        }
        for (int r = 0; r < 20; ++r) {
            float bv = v[0]; int bi = pi[0];
            #pragma unroll
            for (int j = 1; j < 4; ++j)
                if (v[j] > bv || (v[j] == bv && pi[j] < bi)) { bv = v[j]; bi = pi[j]; }
            float rv = bv; int ri = bi;
            #pragma unroll
            for (int off = 32; off; off >>= 1) {
                float ov = __shfl_xor(rv, off, 64);
                int   oi = __shfl_xor(ri, off, 64);
                if (ov > rv || (ov == rv && oi < ri)) { rv = ov; ri = oi; }
            }
            if (lane == 0) { cscore[cls * 20 + r] = rv; cidx[cls * 20 + r] = ri; }
            #pragma unroll
            for (int j = 0; j < 4; ++j) if (pi[j] == ri) v[j] = -1e30f;
        }
    }
    __syncthreads();

    if (t < 100) {
        int cls = t / 20;
        int p = cidx[t];
        int yi = p / WW, xi = p - yi * WW;
        float gx = sigmoidf_(ms[6][p]),  gy = sigmoidf_(ms[7][p]);
        float gw = sigmoidf_(ms[8][p]),  gh = sigmoidf_(ms[9][p]);
        float gd = 3.f * sigmoidf_(ms[10][p]);
        float go = tanhf(ms[11][p]);
        float gs = sigmoidf_(ms[12][p]);
        float gf = sigmoidf_(ms[13][p]);
        float fw = (float)fw_p[0], fh = (float)fh_p[0];
        float sx = fw / (float)WW, sy = fh / (float)HH;
        float cx = fminf(fmaxf((float)xi + gx, 0.f), (float)WW - 1.f) * sx;
        float cy = fminf(fmaxf((float)yi + gy, 0.f), (float)HH - 1.f) * sy;
        float bw = fminf(fmaxf(gw, 0.f), 1.f) * fw;
        float bh = fminf(fmaxf(gh, 0.f), 1.f) * fh;
        float x1 = fminf(fmaxf(cx - bw * 0.5f, 0.f), fw - 1.f);
        float y1 = fminf(fmaxf(cy - bh * 0.5f, 0.f), fh - 1.f);
        float x2 = fminf(fmaxf(cx + bw * 0.5f, 0.f), fw - 1.f);
        float y2 = fminf(fmaxf(cy + bh * 0.5f, 0.f), fh - 1.f);
        dets[t][0] = cscore[t]; dets[t][1] = (float)cls;
        dets[t][2] = gd; dets[t][3] = go; dets[t][4] = gs; dets[t][5] = gf;
        dets[t][6] = x1; dets[t][7] = y1; dets[t][8] = x2; dets[t][9] = y2;
        dvals[t] = gd;
    }
    __syncthreads();
    if (t < 100) {
        float d = dvals[t];
        int rank = 0;
        for (int l = 0; l < 100; ++l) {
            float dl = dvals[l];
            rank += (dl < d) || (dl == d && l < t);
        }
        if (rank < 20) {
            float* o = out + 96 + ((size_t)n * 20 + rank) * 10;
            #pragma unroll
            for (int q = 0; q < 10; ++q) o[q] = dets[t][q];
        }
    }
}

extern "C" void kernel_launch(void* const* d_in, const int* in_sizes, int n_in,
                              void* d_out, int out_size, void* d_ws, size_t ws_size,
                              hipStream_t stream) {
    const float* f    = (const float*)d_in[0];
    const float* w1   = (const float*)d_in[1];
    const float* bng  = (const float*)d_in[2];
    const float* bnb  = (const float*)d_in[3];
    const float* bnm  = (const float*)d_in[4];
    const float* bnv  = (const float*)d_in[5];
    const float* w2   = (const float*)d_in[6];
    const float* b2   = (const float*)d_in[7];
    const float* linW = (const float*)d_in[8];
    const float* linb = (const float*)d_in[9];
    const int*   fw   = (const int*)d_in[10];
    const int*   fh   = (const int*)d_in[11];
    float* out = (float*)d_out;

    const size_t w_elems = (size_t)NHEAD * 9 * 18 * CC * 32;  // 23,887,872
    const size_t f_elems = (size_t)MM * CC;                   //  2,211,840

    ushort_t* ws_whi = (ushort_t*)d_ws;
    ushort_t* ws_wlo = ws_whi + w_elems;
    ushort_t* ws_fhi = ws_wlo + w_elems;
    ushort_t* ws_flo = ws_fhi + f_elems;
    float*    ws_maps = (float*)(ws_flo + f_elems);

    k_single<<<NB, 256, 0, stream>>>(f, linW, linb, out);
    k_prep_w<<<NHEAD * CC, 256, 0, stream>>>(w1, ws_whi, ws_wlo);
    k_prep_f<<<dim3(CC / 32, (PP + 31) / 32, NB), 256, 0, stream>>>(f, ws_fhi, ws_flo);
    k_maps_init<<<(NB * 14 * PP + 255) / 256, 256, 0, stream>>>(ws_maps, b2);
    k_conv_mfma<<<dim3(MM / 256, CC / 64, NHEAD), 256, 0, stream>>>(
        ws_fhi, ws_flo, ws_whi, ws_wlo, w2, bng, bnb, bnm, bnv, ws_maps);
    k_decode<<<NB, 256, 0, stream>>>(ws_maps, fw, fh, out);
}

// Round 5
// 1165.509 us; speedup vs baseline: 1.2319x; 1.2319x over previous
//
#include <hip/hip_runtime.h>
#include <math.h>

#define NB 16
#define CC 576
#define HH 12
#define WW 20
#define PP 240
#define MM 3840
#define NHEAD 8
#define HALO 22

typedef __attribute__((ext_vector_type(8))) short short8;
typedef __attribute__((ext_vector_type(4))) float floatx4;
typedef unsigned short ushort_t;

__device__ __forceinline__ float sigmoidf_(float x) {
    return 1.0f / (1.0f + expf(-x));
}
__device__ __forceinline__ unsigned short f2bf(float x) {
    union { float f; unsigned u; } v; v.f = x;
    unsigned r = v.u + 0x7fff + ((v.u >> 16) & 1);
    return (unsigned short)(r >> 16);
}
__device__ __forceinline__ float bf2f(unsigned short b) {
    union { float f; unsigned u; } v; v.u = ((unsigned)b) << 16;
    return v.f;
}

// ---------------- Kernel A: channel means + linear head + single_out ------
__global__ __launch_bounds__(256) void k_single(const float* __restrict__ f,
                                                const float* __restrict__ linW,
                                                const float* __restrict__ linb,
                                                float* __restrict__ out) {
    int n = blockIdx.x;
    __shared__ float f1[CC];
    __shared__ float lin[10];
    int t = threadIdx.x;
    int lane = t & 63, wave = t >> 6;
    const float* fn = f + (size_t)n * CC * PP;
    for (int c = wave; c < CC; c += 4) {
        const float* row = fn + c * PP;
        float s = 0.f;
        for (int p = lane; p < PP; p += 64) s += row[p];
        #pragma unroll
        for (int off = 32; off; off >>= 1) s += __shfl_xor(s, off, 64);
        if (lane == 0) f1[c] = s * (1.0f / PP);
    }
    __syncthreads();
    if (t < 10) {
        const float* wrow = linW + t * CC;
        float s = linb[t];
        for (int c = 0; c < CC; ++c) s = fmaf(f1[c], wrow[c], s);
        lin[t] = s;
    }
    __syncthreads();
    if (t == 0) {
        const float eps = 1e-5f;
        float conf = sigmoidf_(lin[0]);
        conf = fminf(fmaxf(conf, eps), 1.f - eps);
        int best = 0; float bv = lin[1];
        #pragma unroll
        for (int j = 1; j < 5; ++j) { if (lin[1 + j] > bv) { bv = lin[1 + j]; best = j; } }
        float dist = 3.f * sigmoidf_(lin[6]);
        float offs = tanhf(lin[7]);
        float sev  = fminf(fmaxf(sigmoidf_(lin[8]), eps), 1.f - eps);
        float surf = fminf(fmaxf(sigmoidf_(lin[9]), eps), 1.f - eps);
        float* o = out + n * 6;
        o[0] = conf; o[1] = (float)best; o[2] = dist;
        o[3] = offs; o[4] = sev; o[5] = surf;
    }
}

// ---- prep: f[n][c][p] -> ft_hi/ft_lo in [kgroup8][m][8ch] layout ---------
// o = ((c>>3)*MM + m)*8 + (c&7)  — conv A-staging reads become 1KB/wave.
__global__ __launch_bounds__(256) void k_prep_f(const float* __restrict__ f,
                                                ushort_t* __restrict__ fhi,
                                                ushort_t* __restrict__ flo) {
    __shared__ float tile[32][33];
    int c0 = blockIdx.x * 32, p0 = blockIdx.y * 32, n = blockIdx.z;
    int tp = threadIdx.x & 31, tc8 = threadIdx.x >> 5;
    for (int cc = tc8; cc < 32; cc += 8) {
        int p = p0 + tp;
        tile[cc][tp] = (p < PP) ? f[((size_t)n * CC + c0 + cc) * PP + p] : 0.f;
    }
    __syncthreads();
    int tcw = threadIdx.x & 31, tpw = threadIdx.x >> 5;
    for (int pp = tpw; pp < 32; pp += 8) {
        int p = p0 + pp;
        if (p < PP) {
            float v = tile[tcw][pp];
            unsigned short hi = f2bf(v);
            int m = n * PP + p;
            int c = c0 + tcw;
            size_t o = ((size_t)(c >> 3) * MM + m) * 8 + (c & 7);
            fhi[o] = hi;
            flo[o] = f2bf(v - bf2f(hi));
        }
    }
}

// ------ prep: w1[h][co][ci][tap] -> chunked [h][tap][cib][co][ci32] -------
// Coalesced read of the (h,co) 5184-float row via LDS; ushort2 paired writes.
__global__ __launch_bounds__(256) void k_prep_w(const float* __restrict__ w1,
                                                ushort_t* __restrict__ whi,
                                                ushort_t* __restrict__ wlo) {
    __shared__ float buf[5184];
    int co = blockIdx.x % CC;
    int h  = blockIdx.x / CC;
    const float* src = w1 + (size_t)(h * CC + co) * 5184;
    int t = threadIdx.x;
    for (int i = t; i < 1296; i += 256)
        *(float4*)(buf + 4 * i) = *(const float4*)(src + 4 * i);
    __syncthreads();
    for (int q = t; q < 2592; q += 256) {
        int idx = q * 2;               // idx = tap*CC + ci, ci even
        int tap = idx / CC;
        int ci  = idx - tap * CC;
        float v0 = buf[ci * 9 + tap];
        float v1 = buf[(ci + 1) * 9 + tap];
        unsigned short h0 = f2bf(v0), h1 = f2bf(v1);
        unsigned short l0 = f2bf(v0 - bf2f(h0)), l1 = f2bf(v1 - bf2f(h1));
        int cib = ci >> 5, cr = ci & 31;
        size_t o = (((size_t)(h * 9 + tap) * 18 + cib) * CC + co) * 32 + cr;
        ushort2 ph; ph.x = h0; ph.y = h1;
        ushort2 pl; pl.x = l0; pl.y = l1;
        *(ushort2*)(whi + o) = ph;
        *(ushort2*)(wlo + o) = pl;
    }
}

// ---------------- init maps with bias -------------------------------------
__global__ __launch_bounds__(256) void k_maps_init(float* __restrict__ maps,
                                                   const float* __restrict__ b2) {
    int i = blockIdx.x * 256 + threadIdx.x;
    if (i < NB * 14 * PP) {
        int o = (i / PP) % 14;
        maps[i] = b2[o];
    }
}

// ---------------- fused MFMA conv (bf16x3) + BN + SiLU + projection -------
// grid (15, 9, 8): m-tile 256, co-tile 64, head. 4 waves, wave-tile 64x64.
// A (halo-staged, shared across 9 taps) in LDS; B fragments DIRECT from
// global (fragment-contiguous layout). 2 barriers per ci-chunk.
__global__ __launch_bounds__(256) void k_conv_mfma(
        const ushort_t* __restrict__ fhi, const ushort_t* __restrict__ flo,
        const ushort_t* __restrict__ whi, const ushort_t* __restrict__ wlo,
        const float* __restrict__ w2,
        const float* __restrict__ bng, const float* __restrict__ bnb,
        const float* __restrict__ bnm, const float* __restrict__ bnv,
        float* __restrict__ maps) {
    // fragment-order LDS: chunk(row,g) = (row>>4)*64 + g*16 + (row&15)
    __shared__ __align__(16) ushort_t Ah[1216 * 8];   // 304 rows x 32 k
    __shared__ __align__(16) ushort_t Al[1216 * 8];

    int t = threadIdx.x;
    int m0 = blockIdx.x * 256;
    int c0 = blockIdx.y * 64;
    int h  = blockIdx.z;
    int w = t >> 6, lane = t & 63;
    int quad = lane >> 4, l15 = lane & 15;
    int srow_lo = t & 15, sg = (t >> 4) & 3, srb = t >> 6;

    // zero rows 300..303 (row-block 18, r&15 = 12..15) — never overwritten
    if (t < 32) {
        int arr = t >> 4, g = (t >> 2) & 3, rr = 12 + (t & 3);
        int idx = 18 * 64 + g * 16 + rr;
        short8 z = {0, 0, 0, 0, 0, 0, 0, 0};
        *(short8*)((arr ? Al : Ah) + idx * 8) = z;
    }

    // per-lane A-fragment geometry (i = 0..3)
    int ybase[4], xbase[4], mlb[4];
    #pragma unroll
    for (int i = 0; i < 4; ++i) {
        int ml = w * 64 + i * 16 + l15;
        int m = m0 + ml;
        int p = m % PP;
        ybase[i] = p / WW;
        xbase[i] = p - ybase[i] * WW;
        mlb[i] = ml + HALO;
    }

    floatx4 acc[4][4];
    #pragma unroll
    for (int i = 0; i < 4; ++i)
        #pragma unroll
        for (int j = 0; j < 4; ++j) acc[i][j] = (floatx4){0.f, 0.f, 0.f, 0.f};

    for (int cib = 0; cib < 18; ++cib) {
        __syncthreads();
        int kg = cib * 4 + sg;
        const short8* srch = (const short8*)fhi + (size_t)kg * MM;
        const short8* srcl = (const short8*)flo + (size_t)kg * MM;
        #pragma unroll
        for (int it = 0; it < 5; ++it) {
            int row = (srb + 4 * it) * 16 + srow_lo;
            if (row < 300) {
                int mg = m0 - HALO + row;
                int cidx = 256 * it + t;
                short8 vh = {0, 0, 0, 0, 0, 0, 0, 0};
                short8 vl = {0, 0, 0, 0, 0, 0, 0, 0};
                if ((unsigned)mg < (unsigned)MM) {
                    vh = srch[mg];
                    vl = srcl[mg];
                }
                *(short8*)(Ah + cidx * 8) = vh;
                *(short8*)(Al + cidx * 8) = vl;
            }
        }
        __syncthreads();

        for (int tap = 0; tap < 9; ++tap) {
            int dy = tap / 3 - 1, dx = tap % 3 - 1;
            size_t wbase = (((size_t)(h * 9 + tap) * 18 + cib) * CC) * 32;
            const ushort_t* wbh = whi + wbase;
            const ushort_t* wbl = wlo + wbase;

            short8 ah[4], al[4];
            #pragma unroll
            for (int i = 0; i < 4; ++i) {
                int yy = ybase[i] + dy, xx = xbase[i] + dx;
                int r = ((unsigned)yy < (unsigned)HH && (unsigned)xx < (unsigned)WW)
                          ? (mlb[i] + dy * WW + dx) : (300 + (l15 & 3));
                int a16 = ((r >> 4) * 64 + quad * 16 + (r & 15)) * 8;
                ah[i] = *(const short8*)(Ah + a16);
                al[i] = *(const short8*)(Al + a16);
            }
            #pragma unroll
            for (int j = 0; j < 4; ++j) {
                int off = (c0 + j * 16 + l15) * 32 + quad * 8;
                short8 bh = *(const short8*)(wbh + off);
                short8 bl = *(const short8*)(wbl + off);
                #pragma unroll
                for (int i = 0; i < 4; ++i) {
                    acc[i][j] = __builtin_amdgcn_mfma_f32_16x16x32_bf16(
                        ah[i], bh, acc[i][j], 0, 0, 0);
                    acc[i][j] = __builtin_amdgcn_mfma_f32_16x16x32_bf16(
                        ah[i], bl, acc[i][j], 0, 0, 0);
                    acc[i][j] = __builtin_amdgcn_mfma_f32_16x16x32_bf16(
                        al[i], bh, acc[i][j], 0, 0, 0);
                }
            }
        }
    }

    // ---- epilogue: BN + SiLU, then fused projection ----
    float scale[4], shift[4];
    #pragma unroll
    for (int j = 0; j < 4; ++j) {
        int c = h * CC + c0 + j * 16 + l15;
        float g_ = bng[c], bb = bnb[c], bm = bnm[c], bv = bnv[c];
        scale[j] = g_ / sqrtf(bv + 1e-5f);
        shift[j] = bb - bm * scale[j];
    }
    #pragma unroll
    for (int i = 0; i < 4; ++i)
        #pragma unroll
        for (int j = 0; j < 4; ++j)
            #pragma unroll
            for (int r = 0; r < 4; ++r) {
                float hx = fmaf(acc[i][j][r], scale[j], shift[j]);
                acc[i][j][r] = hx * sigmoidf_(hx);
            }

    static const int OFFo[NHEAD + 1] = {0, 5, 6, 8, 10, 11, 12, 13, 14};
    int o0 = OFFo[h], o1 = OFFo[h + 1];
    for (int o = o0; o < o1; ++o) {
        float w2v[4];
        #pragma unroll
        for (int j = 0; j < 4; ++j) w2v[j] = w2[o * CC + c0 + j * 16 + l15];
        float pv[4][4];
        #pragma unroll
        for (int i = 0; i < 4; ++i)
            #pragma unroll
            for (int r = 0; r < 4; ++r) {
                float s = 0.f;
                #pragma unroll
                for (int j = 0; j < 4; ++j) s = fmaf(acc[i][j][r], w2v[j], s);
                pv[i][r] = s;
            }
        #pragma unroll
        for (int off = 1; off < 16; off <<= 1)
            #pragma unroll
            for (int i = 0; i < 4; ++i)
                #pragma unroll
                for (int r = 0; r < 4; ++r)
                    pv[i][r] += __shfl_xor(pv[i][r], off, 64);
        if (l15 == 0) {
            #pragma unroll
            for (int i = 0; i < 4; ++i)
                #pragma unroll
                for (int r = 0; r < 4; ++r) {
                    int m = m0 + w * 64 + i * 16 + quad * 4 + r;
                    int n = m / PP, p = m - n * PP;
                    atomicAdd(&maps[(n * 14 + o) * PP + p], pv[i][r]);
                }
        }
    }
}

// ---------------- Kernel D: decode + top-k + distance sort ----------------
__global__ __launch_bounds__(256) void k_decode(
        const float* __restrict__ maps,
        const int* __restrict__ fw_p, const int* __restrict__ fh_p,
        float* __restrict__ out) {
    int n = blockIdx.x;
    int t = threadIdx.x;
    __shared__ float ms[14][PP];
    __shared__ float sconf[PP];
    __shared__ float cscore[100];
    __shared__ int   cidx[100];
    __shared__ float dets[100][10];
    __shared__ float dvals[100];

    const float* mp = maps + (size_t)n * 14 * PP;
    for (int idx = t; idx < 14 * PP; idx += 256) ms[idx / PP][idx % PP] = mp[idx];
    __syncthreads();
    if (t < PP) sconf[t] = sigmoidf_(ms[5][t]);
    __syncthreads();

    int wv = t >> 6, lane = t & 63;
    for (int cls = wv; cls < 5; cls += 4) {
        float v[4]; int pi[4];
        #pragma unroll
        for (int j = 0; j < 4; ++j) {
            int p = lane + 64 * j;
            pi[j] = p;
            v[j] = (p < PP) ? sconf[p] * sigmoidf_(ms[cls][p]) : -1e30f;
        }
        for (int r = 0; r < 20; ++r) {
            float bv = v[0]; int bi = pi[0];
            #pragma unroll
            for (int j = 1; j < 4; ++j)
                if (v[j] > bv || (v[j] == bv && pi[j] < bi)) { bv = v[j]; bi = pi[j]; }
            float rv = bv; int ri = bi;
            #pragma unroll
            for (int off = 32; off; off >>= 1) {
                float ov = __shfl_xor(rv, off, 64);
                int   oi = __shfl_xor(ri, off, 64);
                if (ov > rv || (ov == rv && oi < ri)) { rv = ov; ri = oi; }
            }
            if (lane == 0) { cscore[cls * 20 + r] = rv; cidx[cls * 20 + r] = ri; }
            #pragma unroll
            for (int j = 0; j < 4; ++j) if (pi[j] == ri) v[j] = -1e30f;
        }
    }
    __syncthreads();

    if (t < 100) {
        int cls = t / 20;
        int p = cidx[t];
        int yi = p / WW, xi = p - yi * WW;
        float gx = sigmoidf_(ms[6][p]),  gy = sigmoidf_(ms[7][p]);
        float gw = sigmoidf_(ms[8][p]),  gh = sigmoidf_(ms[9][p]);
        float gd = 3.f * sigmoidf_(ms[10][p]);
        float go = tanhf(ms[11][p]);
        float gs = sigmoidf_(ms[12][p]);
        float gf = sigmoidf_(ms[13][p]);
        float fw = (float)fw_p[0], fh = (float)fh_p[0];
        float sx = fw / (float)WW, sy = fh / (float)HH;
        float cx = fminf(fmaxf((float)xi + gx, 0.f), (float)WW - 1.f) * sx;
        float cy = fminf(fmaxf((float)yi + gy, 0.f), (float)HH - 1.f) * sy;
        float bw = fminf(fmaxf(gw, 0.f), 1.f) * fw;
        float bh = fminf(fmaxf(gh, 0.f), 1.f) * fh;
        float x1 = fminf(fmaxf(cx - bw * 0.5f, 0.f), fw - 1.f);
        float y1 = fminf(fmaxf(cy - bh * 0.5f, 0.f), fh - 1.f);
        float x2 = fminf(fmaxf(cx + bw * 0.5f, 0.f), fw - 1.f);
        float y2 = fminf(fmaxf(cy + bh * 0.5f, 0.f), fh - 1.f);
        dets[t][0] = cscore[t]; dets[t][1] = (float)cls;
        dets[t][2] = gd; dets[t][3] = go; dets[t][4] = gs; dets[t][5] = gf;
        dets[t][6] = x1; dets[t][7] = y1; dets[t][8] = x2; dets[t][9] = y2;
        dvals[t] = gd;
    }
    __syncthreads();
    if (t < 100) {
        float d = dvals[t];
        int rank = 0;
        for (int l = 0; l < 100; ++l) {
            float dl = dvals[l];
            rank += (dl < d) || (dl == d && l < t);
        }
        if (rank < 20) {
            float* o = out + 96 + ((size_t)n * 20 + rank) * 10;
            #pragma unroll
            for (int q = 0; q < 10; ++q) o[q] = dets[t][q];
        }
    }
}

extern "C" void kernel_launch(void* const* d_in, const int* in_sizes, int n_in,
                              void* d_out, int out_size, void* d_ws, size_t ws_size,
                              hipStream_t stream) {
    const float* f    = (const float*)d_in[0];
    const float* w1   = (const float*)d_in[1];
    const float* bng  = (const float*)d_in[2];
    const float* bnb  = (const float*)d_in[3];
    const float* bnm  = (const float*)d_in[4];
    const float* bnv  = (const float*)d_in[5];
    const float* w2   = (const float*)d_in[6];
    const float* b2   = (const float*)d_in[7];
    const float* linW = (const float*)d_in[8];
    const float* linb = (const float*)d_in[9];
    const int*   fw   = (const int*)d_in[10];
    const int*   fh   = (const int*)d_in[11];
    float* out = (float*)d_out;

    const size_t w_elems = (size_t)NHEAD * 9 * 18 * CC * 32;  // 23,887,872
    const size_t f_elems = (size_t)72 * MM * 8;               //  2,211,840

    ushort_t* ws_whi = (ushort_t*)d_ws;
    ushort_t* ws_wlo = ws_whi + w_elems;
    ushort_t* ws_fhi = ws_wlo + w_elems;
    ushort_t* ws_flo = ws_fhi + f_elems;
    float*    ws_maps = (float*)(ws_flo + f_elems);

    k_single<<<NB, 256, 0, stream>>>(f, linW, linb, out);
    k_prep_w<<<NHEAD * CC, 256, 0, stream>>>(w1, ws_whi, ws_wlo);
    k_prep_f<<<dim3(CC / 32, (PP + 31) / 32, NB), 256, 0, stream>>>(f, ws_fhi, ws_flo);
    k_maps_init<<<(NB * 14 * PP + 255) / 256, 256, 0, stream>>>(ws_maps, b2);
    k_conv_mfma<<<dim3(MM / 256, CC / 64, NHEAD), 256, 0, stream>>>(
        ws_fhi, ws_flo, ws_whi, ws_wlo, w2, bng, bnb, bnm, bnv, ws_maps);
    k_decode<<<NB, 256, 0, stream>>>(ws_maps, fw, fh, out);
}